// Round 14
// baseline (271.052 us; speedup 1.0000x reference)
//
#include <hip/hip_runtime.h>

typedef __attribute__((ext_vector_type(8))) __bf16 bf16x8;
typedef __attribute__((ext_vector_type(8))) unsigned short u16x8;
typedef __attribute__((ext_vector_type(4))) float f32x4;

// Static device scratch (bf16 unless noted):
//  xbf [2048][2048], WtQKV [3072][2048], WtO [2048][2048],
//  q [2048][2048], k [2048][512], vt [2][4][128][1024], att [2048][2048],
//  PO f32 [2ch][32768 rows][128], PML f32 [2ch][32768 rows][6]
#define XBOFF 0
#define WQKVOFF (XBOFF + 2048 * 2048)
#define WOOFF   (WQKVOFF + 3072 * 2048)
#define QOFF    (WOOFF + 2048 * 2048)
#define KOFF    (QOFF + 2048 * 2048)
#define VTOFF   (KOFF + 2048 * 512)     // V pre-transposed: [b][g][d=128][s=1024]
#define AOFF    (VTOFF + 2048 * 512)
#define POOFF   (AOFF + 2048 * 2048)                 // f32 partial O (unnormalized)
#define PMLOFF  (POOFF + 2 * 32768 * 128 * 2)        // f32 per-level m,l (base-2 domain)
__device__ __align__(16) ushort g_scratch[PMLOFF + 2 * 32768 * 6 * 2];

// nested (matryoshka) index -> full-layout index, H heads/groups, 128/head
__device__ __forceinline__ int nest_map(int n, int H) {
    int h = n >> 7, j = n & 127;
    if (j < 32) return h * 32 + j;
    if (j < 64) return H * 32 + h * 32 + (j - 32);
    return H * 64 + h * 64 + (j - 64);
}

__device__ __forceinline__ ushort f2bf(float f) {
    unsigned u = __builtin_bit_cast(unsigned, f);
    u += 0x7fffu + ((u >> 16) & 1u);
    return (ushort)(u >> 16);
}
__device__ __forceinline__ bf16x8 ld_frag(const ushort* p) {
    return __builtin_bit_cast(bf16x8, *(const u16x8*)p);
}
// bare v_exp_f32 (2^x) — __exp2f does not exist in HIP headers (R10 lesson)
__device__ __forceinline__ float exp2_fast(float x) {
    return __builtin_amdgcn_exp2f(x);
}
// async 16B global->LDS (m97 pattern); LDS base must be wave-uniform
__device__ __forceinline__ void glds16(const ushort* g, ushort* s) {
    __builtin_amdgcn_global_load_lds(
        (const __attribute__((address_space(1))) void*)g,
        (__attribute__((address_space(3))) void*)s, 16, 0, 0);
}

// ---------------------------------------------------------------------------
// Fused prep: one dispatch does x cvt + all 4 weight transposes.
// blocks [0,2048): x fp32->bf16.  [2048,3072): Wq^T  [3072,3328): Wk^T
// [3328,3584): Wv^T  [3584,4608): Wo^T (row-mapped)
// ---------------------------------------------------------------------------
__global__ __launch_bounds__(256) void prep_kernel(
    const float* __restrict__ x,
    const float* __restrict__ Wq, const float* __restrict__ Wk,
    const float* __restrict__ Wv, const float* __restrict__ Wo)
{
    const int bx = blockIdx.x;
    const int tid = threadIdx.x;

    if (bx < 2048) {   // ---- x convert ----
        size_t i = ((size_t)bx * 256 + tid) * 8;
        float4 f0 = *(const float4*)&x[i];
        float4 f1 = *(const float4*)&x[i + 4];
        union { uint4 v; ushort u[8]; } a;
        a.u[0] = f2bf(f0.x); a.u[1] = f2bf(f0.y); a.u[2] = f2bf(f0.z); a.u[3] = f2bf(f0.w);
        a.u[4] = f2bf(f1.x); a.u[5] = f2bf(f1.y); a.u[6] = f2bf(f1.z); a.u[7] = f2bf(f1.w);
        *(uint4*)&g_scratch[XBOFF + i] = a.v;
        return;
    }

    const float* W; int rowlen, H, mode, dstoff, t;
    if (bx < 3072)      { W = Wq; rowlen = 2048; H = 16; mode = 0; dstoff = WQKVOFF;               t = bx - 2048; }
    else if (bx < 3328) { W = Wk; rowlen = 512;  H = 4;  mode = 0; dstoff = WQKVOFF + 2048 * 2048; t = bx - 3072; }
    else if (bx < 3584) { W = Wv; rowlen = 512;  H = 4;  mode = 0; dstoff = WQKVOFF + 2560 * 2048; t = bx - 3328; }
    else                { W = Wo; rowlen = 2048; H = 16; mode = 1; dstoff = WOOFF;                 t = bx - 3584; }
    const int k0 = (t & 31) * 64;
    const int n0 = (t >> 5) * 64;

    __shared__ ushort T[64][66];
    const int r = tid >> 3, oct = tid & 7;

    #pragma unroll
    for (int rep = 0; rep < 2; ++rep) {
        int rr = r + rep * 32;
        int wrow = mode ? nest_map(k0 + rr, 16) : (k0 + rr);
        int wcol = mode ? (n0 + oct * 8) : nest_map(n0 + oct * 8, H);
        float4 f0 = *(const float4*)&W[(size_t)wrow * rowlen + wcol];
        float4 f1 = *(const float4*)&W[(size_t)wrow * rowlen + wcol + 4];
        ushort* d = &T[rr][oct * 8];
        d[0] = f2bf(f0.x); d[1] = f2bf(f0.y); d[2] = f2bf(f0.z); d[3] = f2bf(f0.w);
        d[4] = f2bf(f1.x); d[5] = f2bf(f1.y); d[6] = f2bf(f1.z); d[7] = f2bf(f1.w);
    }
    __syncthreads();
    #pragma unroll
    for (int rep = 0; rep < 2; ++rep) {
        int rr = r + rep * 32;
        union { uint4 v; ushort u[8]; } cv;
        #pragma unroll
        for (int i = 0; i < 8; ++i) cv.u[i] = T[oct * 8 + i][rr];
        *(uint4*)&g_scratch[dstoff + (size_t)(n0 + rr) * 2048 + k0 + oct * 8] = cv.v;
    }
}

// ---------------------------------------------------------------------------
// 128x128-tile GEMM, BK=64 (R13 — unchanged this round). Counted-vmcnt
// 2-buffer pipeline; rect per-XCD chunks.
// ---------------------------------------------------------------------------
__global__ __launch_bounds__(256) void gemm128_kernel(
    const float* __restrict__ b0, const float* __restrict__ b1,
    const float* __restrict__ b2, float* __restrict__ oext, int mode)
{
    __shared__ __align__(16) ushort SH[2 * 16384];

    const int gx = gridDim.x;             // n tiles (mult of 4)
    const int gy = gridDim.y;             // m tiles (mult of 2)
    const int id = blockIdx.x + gx * blockIdx.y;
    const int xcd = id & 7, idl = id >> 3;
    const int CM = gy >> 1, CN = gx >> 2; // 2x4 chunk grid over 8 XCDs
    const int m_idx = (xcd >> 2) * CM + (idl % CM);
    const int n_idx = (xcd & 3) * CN + (idl / CM);
    const int n0 = n_idx * 128;
    const int m0 = m_idx * 128;

    const int tid = threadIdx.x;
    const int lane = tid & 63, wid = tid >> 6;
    const int wm = wid & 1, wn = wid >> 1;
    const int quad = lane >> 4, l16 = lane & 15;

    const ushort* A  = g_scratch + (mode ? AOFF : XBOFF);
    const ushort* Bt = g_scratch + (mode ? WOOFF : WQKVOFF);

    const bool vpath = (mode == 0) && (n0 >= 2560);
    const float* bias; ushort* outS = nullptr; int c0, oldim, H;
    if (mode == 1)      { bias = b0; c0 = n0; oldim = 2048; H = 0; }
    else if (n0 < 2048) { bias = b0; outS = g_scratch + QOFF; c0 = n0;        oldim = 2048; H = 16; }
    else if (n0 < 2560) { bias = b1; outS = g_scratch + KOFF; c0 = n0 - 2048; oldim = 512;  H = 4; }
    else                { bias = b2; outS = nullptr;          c0 = n0 - 2560; oldim = 512;  H = 4; }

    const int lrow = lane >> 3;
    const int lchunk = (lane & 7) ^ (lrow & 7);

    f32x4 acc[4][4];
    #pragma unroll
    for (int a = 0; a < 4; ++a)
        #pragma unroll
        for (int c = 0; c < 4; ++c) acc[a][c] = f32x4{0.f, 0.f, 0.f, 0.f};

    auto STAGE = [&](int buf, int kt) {
        const int k0 = kt * 64;
        ushort* as_ = SH + buf * 16384;
        ushort* bs_ = as_ + 8192;
        #pragma unroll
        for (int it = 0; it < 4; ++it) {      // A: 128 rows
            int rb = it * 32 + wid * 8;       // wave-uniform row base
            int r  = rb + lrow;
            glds16(&A[(size_t)(m0 + r) * 2048 + k0 + lchunk * 8], &as_[rb * 64]);
        }
        #pragma unroll
        for (int it = 0; it < 4; ++it) {      // B: 128 rows
            int rb = it * 32 + wid * 8;
            int r  = rb + lrow;
            glds16(&Bt[(size_t)(n0 + r) * 2048 + k0 + lchunk * 8], &bs_[rb * 64]);
        }
    };

    STAGE(0, 0);
    STAGE(1, 1);

    for (int kt = 0; kt < 32; ++kt) {
        if (kt < 31) asm volatile("s_waitcnt vmcnt(8)" ::: "memory");
        else         asm volatile("s_waitcnt vmcnt(0)" ::: "memory");
        __builtin_amdgcn_s_barrier();         // all waves' kt-loads landed

        const ushort* as_ = SH + (kt & 1) * 16384;
        const ushort* bs_ = as_ + 8192;
        #pragma unroll
        for (int kc = 0; kc < 2; ++kc) {
            bf16x8 af[4], bf[4];
            #pragma unroll
            for (int s = 0; s < 4; ++s) {
                int ra = wm * 64 + s * 16 + l16;
                int rbv = wn * 64 + s * 16 + l16;
                int ch = kc * 4 + quad;
                af[s] = ld_frag(&as_[ra * 64 + ((ch ^ (ra & 7)) * 8)]);
                bf[s] = ld_frag(&bs_[rbv * 64 + ((ch ^ (rbv & 7)) * 8)]);
            }
            #pragma unroll
            for (int sm = 0; sm < 4; ++sm)
                #pragma unroll
                for (int sn = 0; sn < 4; ++sn)
                    acc[sm][sn] = __builtin_amdgcn_mfma_f32_16x16x32_bf16(
                        af[sm], bf[sn], acc[sm][sn], 0, 0, 0);
        }
        __builtin_amdgcn_s_barrier();         // all reads of buf[kt&1] done
        if (kt <= 29) STAGE(kt & 1, kt + 2);  // safe to overwrite; async
    }
    __syncthreads();   // drain before epilogue reuses SH

    if (vpath) {
        // transpose 128x128 tile through SH (xor-swizzled), write vt[b][g][d][s]
        #pragma unroll
        for (int sm = 0; sm < 4; ++sm)
        #pragma unroll
        for (int sn = 0; sn < 4; ++sn)
        #pragma unroll
        for (int i = 0; i < 4; ++i) {
            int r = wm * 64 + sm * 16 + quad * 4 + i;       // spos-local
            int loc = wn * 64 + sn * 16 + l16;              // d-local (=g*128+d col)
            float v = acc[sm][sn][i] + bias[nest_map(c0 + loc, 4)];
            SH[loc * 128 + (r ^ ((loc & 7) << 3))] = f2bf(v);
        }
        __syncthreads();
        const int dloc = tid >> 1, half = tid & 1;
        const int gg = c0 >> 7, bb = m0 >> 10, sb = m0 & 1023;
        ushort* vt = g_scratch + VTOFF;
        #pragma unroll
        for (int j = 0; j < 8; ++j) {
            int r = half * 64 + j * 8;
            uint4 v = *(uint4*)&SH[dloc * 128 + (r ^ ((dloc & 7) << 3))];
            *(uint4*)&vt[((size_t)((bb * 4 + gg) * 128 + dloc)) * 1024 + sb + r] = v;
        }
    } else {
        #pragma unroll
        for (int sm = 0; sm < 4; ++sm)
        #pragma unroll
        for (int sn = 0; sn < 4; ++sn)
        #pragma unroll
        for (int i = 0; i < 4; ++i) {
            int row = m0 + wm * 64 + sm * 16 + quad * 4 + i;
            int loc = wn * 64 + sn * 16 + l16;
            float v = acc[sm][sn][i];
            if (mode == 1) {
                oext[(size_t)row * 2048 + c0 + loc] = v + bias[c0 + loc];
            } else {
                v += bias[nest_map(c0 + loc, H)];
                outS[(size_t)row * oldim + c0 + loc] = f2bf(v);
            }
        }
    }
}

// ---------------------------------------------------------------------------
// Matryoshka flash attention, 2-way split-K v2. Grid (32,16,2):
// x = qt_idx*2 + c; qt = (h&8) ? qt_idx : 15-qt_idx  <-- h-DEPENDENT mapping
// so the round-robin co-resident set {id, id+256, id+512, id+768} (same x,
// h differing by 8) holds chunks of (a+1)/2 and (16-a)/2 tiles: every CU
// gets exactly ~17 half-units (R2's failure was same-size co-residents).
// 1024 blocks = 4/CU; LDS 40960 B x 4 = exactly 160 KiB -> 4 RESIDENT
// blocks (16 waves/CU, 2x today's latency hiding for a VALU-latency-bound
// kernel). Chunk c=0: kt in [0, nk/2); c=1: [nk/2, nk) incl. diag.
// Internals = R11 (base-2 softmax, MFMA row-sum, XOR LDS, setprio).
// Epilogue writes unnormalized PO (fp32) + per-level (m,l) in base-2 domain;
// merge_kernel combines.
// ---------------------------------------------------------------------------
__global__ __launch_bounds__(256) void attn_kernel()
{
    const ushort* qb = g_scratch + QOFF;   // [B,S,16,128] nested
    const ushort* kb = g_scratch + KOFF;   // [B,S,4,128]
    const ushort* vt = g_scratch + VTOFF;  // [B,4,128,1024]
    float* PO  = (float*)(g_scratch + POOFF);
    float* PML = (float*)(g_scratch + PMLOFF);

    __shared__ __align__(16) ushort Ks[64 * 128];
    __shared__ __align__(16) ushort Vt[128 * 64];
    __shared__ __align__(16) ushort Ps[64 * 64];

    const int x = blockIdx.x, h = blockIdx.y, b = blockIdx.z;
    const int qt_idx = x >> 1, c = x & 1;
    const int qt = (h & 8) ? qt_idx : (15 - qt_idx);   // h-anticorrelated
    const int nk = qt + 1, half = nk >> 1;
    const int lo = c ? half : 0, hi = c ? nk : half;
    const int g = h >> 2;
    const int q0 = qt * 64;
    const int tid = threadIdx.x;
    const int lane = tid & 63, w = tid >> 6;
    const int quad = lane >> 4, l16 = lane & 15;

    // base-2-domain scales: (1/sqrt(d)) * log2(e)
    const float sc0 = 0.25503639f;
    const float sc1 = 0.18033688f;
    const float sc2 = 0.12751820f;

    bf16x8 qa[4];
    {
        const ushort* qrow =
            qb + ((size_t)((b * 1024 + q0 + w * 16 + l16) * 16 + h)) * 128;
        #pragma unroll
        for (int kc = 0; kc < 4; ++kc)
            qa[kc] = ld_frag(qrow + kc * 32 + quad * 8);
    }

    float m_s[3][4], l_s[3][4];
    #pragma unroll
    for (int l = 0; l < 3; ++l)
        #pragma unroll
        for (int i = 0; i < 4; ++i) { m_s[l][i] = -1e9f; l_s[l][i] = 0.0f; }
    f32x4 oacc[8];
    #pragma unroll
    for (int t2 = 0; t2 < 8; ++t2) oacc[t2] = f32x4{0.f, 0.f, 0.f, 0.f};
    const f32x4 fz = {0.f, 0.f, 0.f, 0.f};
    const bf16x8 ones = __builtin_bit_cast(bf16x8, u16x8{
        0x3F80, 0x3F80, 0x3F80, 0x3F80, 0x3F80, 0x3F80, 0x3F80, 0x3F80});

    for (int kt = lo; kt < hi; ++kt) {
        const int k0 = kt * 64;
        {   // stage K (b128, swizzled) + Vt from global vt (b128, swizzled)
            int r16 = tid >> 4, oct16 = tid & 15;
            #pragma unroll
            for (int rep = 0; rep < 4; ++rep) {
                int row = r16 + rep * 16;
                *(uint4*)&Ks[row * 128 + ((oct16 ^ (row & 7)) * 8)] =
                    *(const uint4*)&kb[(size_t)((b * 1024 + k0 + row) * 4 + g) * 128 + oct16 * 8];
            }
            int oct = tid & 7, dr = tid >> 3;
            #pragma unroll
            for (int rep = 0; rep < 4; ++rep) {
                int d = dr + rep * 32;
                *(uint4*)&Vt[d * 64 + ((oct ^ (d & 7)) * 8)] =
                    *(const uint4*)&vt[((size_t)((b * 4 + g) * 128 + d)) * 1024 + k0 + oct * 8];
            }
        }
        __syncthreads();

        const bool diag = (kt == qt);

        // QK^T, cumulative snapshots: s0 (dims 0:32), s1 (0:64), s2 (0:128)
        f32x4 s0[4], s1[4], s2[4];
        __builtin_amdgcn_s_setprio(1);
        #pragma unroll
        for (int n = 0; n < 4; ++n) {
            int r = n * 16 + l16;
            s0[n] = __builtin_amdgcn_mfma_f32_16x16x32_bf16(
                qa[0], ld_frag(&Ks[r * 128 + (((0 + quad) ^ (r & 7)) * 8)]), fz, 0, 0, 0);
        }
        #pragma unroll
        for (int n = 0; n < 4; ++n) {
            int r = n * 16 + l16;
            s1[n] = __builtin_amdgcn_mfma_f32_16x16x32_bf16(
                qa[1], ld_frag(&Ks[r * 128 + (((4 + quad) ^ (r & 7)) * 8)]), s0[n], 0, 0, 0);
        }
        #pragma unroll
        for (int n = 0; n < 4; ++n) {
            int r = n * 16 + l16;
            s2[n] = __builtin_amdgcn_mfma_f32_16x16x32_bf16(
                qa[2], ld_frag(&Ks[r * 128 + (((8 + quad) ^ (r & 7)) * 8)]), s1[n], 0, 0, 0);
        }
        #pragma unroll
        for (int n = 0; n < 4; ++n) {
            int r = n * 16 + l16;
            s2[n] = __builtin_amdgcn_mfma_f32_16x16x32_bf16(
                qa[3], ld_frag(&Ks[r * 128 + (((12 + quad) ^ (r & 7)) * 8)]), s2[n], 0, 0, 0);
        }
        __builtin_amdgcn_s_setprio(0);

        // interleaved 3-level online softmax, base-2 domain (ILP chains)
        float sv[3][4][4], mx[3][4];
        #pragma unroll
        for (int l = 0; l < 3; ++l)
            #pragma unroll
            for (int i = 0; i < 4; ++i) mx[l][i] = -1e9f;
        #pragma unroll
        for (int n = 0; n < 4; ++n)
            #pragma unroll
            for (int i = 0; i < 4; ++i) {
                bool msk = diag &&
                    (k0 + n * 16 + l16 > q0 + w * 16 + quad * 4 + i);
                float x0 = msk ? -1e9f : s0[n][i] * sc0;
                float x1 = msk ? -1e9f : s1[n][i] * sc1;
                float x2 = msk ? -1e9f : s2[n][i] * sc2;
                sv[0][n][i] = x0; mx[0][i] = fmaxf(mx[0][i], x0);
                sv[1][n][i] = x1; mx[1][i] = fmaxf(mx[1][i], x1);
                sv[2][n][i] = x2; mx[2][i] = fmaxf(mx[2][i], x2);
            }
        #pragma unroll
        for (int d = 1; d < 16; d <<= 1)
            #pragma unroll
            for (int l = 0; l < 3; ++l)
                #pragma unroll
                for (int i = 0; i < 4; ++i)
                    mx[l][i] = fmaxf(mx[l][i], __shfl_xor(mx[l][i], d, 64));
        float al[3][4];
        #pragma unroll
        for (int l = 0; l < 3; ++l)
            #pragma unroll
            for (int i = 0; i < 4; ++i) {
                float mn = fmaxf(m_s[l][i], mx[l][i]);
                al[l][i] = exp2_fast(m_s[l][i] - mn);
                m_s[l][i] = mn;
            }
        #pragma unroll
        for (int n = 0; n < 4; ++n)
            #pragma unroll
            for (int l = 0; l < 3; ++l)
                #pragma unroll
                for (int i = 0; i < 4; ++i)
                    sv[l][n][i] = exp2_fast(sv[l][n][i] - m_s[l][i]);
        #pragma unroll
        for (int t = 0; t < 8; ++t) {
            int lvl = (t < 2) ? 0 : (t < 4) ? 1 : 2;
            #pragma unroll
            for (int i = 0; i < 4; ++i) oacc[t][i] *= al[lvl][i];
        }

        // per-level Ps roundtrip + PV + MFMA row-sum (same-wave in-order LDS)
        f32x4 racc[3];
        const int obase[3] = {0, 2, 4}, onts[3] = {2, 2, 4}, voffs[3] = {0, 32, 64};
        #pragma unroll
        for (int l = 0; l < 3; ++l) {
            #pragma unroll
            for (int n = 0; n < 4; ++n)
                #pragma unroll
                for (int i = 0; i < 4; ++i) {
                    int prow = w * 16 + quad * 4 + i;
                    int col = n * 16 + l16;
                    Ps[prow * 64 + ((((col >> 3) ^ (prow & 7)) << 3) | (col & 7))] =
                        f2bf(sv[l][n][i]);
                }
            racc[l] = fz;
            __builtin_amdgcn_s_setprio(1);
            #pragma unroll
            for (int kc = 0; kc < 2; ++kc) {
                int prow = w * 16 + l16;
                bf16x8 pa = ld_frag(&Ps[prow * 64 + (((kc * 4 + quad) ^ (prow & 7)) * 8)]);
                racc[l] = __builtin_amdgcn_mfma_f32_16x16x32_bf16(
                    pa, ones, racc[l], 0, 0, 0);
                #pragma unroll
                for (int t = 0; t < 4; ++t) {
                    if (t < onts[l]) {
                        int vd = voffs[l] + t * 16 + l16;
                        bf16x8 vf = ld_frag(&Vt[vd * 64 + (((kc * 4 + quad) ^ (vd & 7)) * 8)]);
                        oacc[obase[l] + t] = __builtin_amdgcn_mfma_f32_16x16x32_bf16(
                            pa, vf, oacc[obase[l] + t], 0, 0, 0);
                    }
                }
            }
            __builtin_amdgcn_s_setprio(0);
        }
        #pragma unroll
        for (int l = 0; l < 3; ++l)
            #pragma unroll
            for (int i = 0; i < 4; ++i)
                l_s[l][i] = l_s[l][i] * al[l][i] + racc[l][i];
        __syncthreads();   // WAR: Ks/Vt reads done before next staging
    }

    // write unnormalized partial O (fp32) + per-level (m,l), base-2 domain
    const size_t rowbase = ((size_t)(c * 2 + b) * 16 + h) * 1024;
    #pragma unroll
    for (int t = 0; t < 8; ++t) {
        #pragma unroll
        for (int i = 0; i < 4; ++i) {
            int srow = q0 + w * 16 + quad * 4 + i;
            PO[(rowbase + srow) * 128 + t * 16 + l16] = oacc[t][i];
        }
    }
    #pragma unroll
    for (int lvl = 0; lvl < 3; ++lvl) {
        if ((l16 >> 1) == lvl && l16 < 6) {
            bool isl = (l16 & 1);
            #pragma unroll
            for (int i = 0; i < 4; ++i) {
                int srow = q0 + w * 16 + quad * 4 + i;
                PML[(rowbase + srow) * 6 + l16] = isl ? l_s[lvl][i] : m_s[lvl][i];
            }
        }
    }
}

// ---------------------------------------------------------------------------
// Merge the two split-K chunks: att = (w0*O0 + w1*O1) / (w0*l0 + w1*l1),
// w_c = exp2(m_c - max(m0,m1)) (m in base-2 domain), per matryoshka level.
// 524288 threads, each handles 8 dims of one (b,h,s) row. Pure BW (~50 MB).
// ---------------------------------------------------------------------------
__global__ __launch_bounds__(256) void merge_kernel()
{
    const float* PO  = (const float*)(g_scratch + POOFF);
    const float* PML = (const float*)(g_scratch + PMLOFF);
    ushort* att = g_scratch + AOFF;

    const int idx = blockIdx.x * 256 + threadIdx.x;
    const int R = idx >> 4;            // (b*16+h)*1024 + s
    const int seg = idx & 15;
    const int lvl = (seg < 4) ? 0 : (seg < 8) ? 1 : 2;
    const int NR = 32768;

    float m0 = PML[(size_t)(0 * NR + R) * 6 + 2 * lvl];
    float l0 = PML[(size_t)(0 * NR + R) * 6 + 2 * lvl + 1];
    float m1 = PML[(size_t)(1 * NR + R) * 6 + 2 * lvl];
    float l1 = PML[(size_t)(1 * NR + R) * 6 + 2 * lvl + 1];
    float M = fmaxf(m0, m1);
    float w0 = exp2_fast(m0 - M), w1 = exp2_fast(m1 - M);
    float den = w0 * l0 + w1 * l1;
    float inv = (den > 0.f) ? (1.0f / den) : 0.f;
    w0 *= inv; w1 *= inv;

    const int d0 = seg * 8;
    float4 a0 = *(const float4*)&PO[((size_t)(0 * NR + R)) * 128 + d0];
    float4 a1 = *(const float4*)&PO[((size_t)(0 * NR + R)) * 128 + d0 + 4];
    float4 c0 = *(const float4*)&PO[((size_t)(1 * NR + R)) * 128 + d0];
    float4 c1 = *(const float4*)&PO[((size_t)(1 * NR + R)) * 128 + d0 + 4];

    union { uint4 v; ushort u[8]; } o;
    o.u[0] = f2bf(w0 * a0.x + w1 * c0.x);
    o.u[1] = f2bf(w0 * a0.y + w1 * c0.y);
    o.u[2] = f2bf(w0 * a0.z + w1 * c0.z);
    o.u[3] = f2bf(w0 * a0.w + w1 * c0.w);
    o.u[4] = f2bf(w0 * a1.x + w1 * c1.x);
    o.u[5] = f2bf(w0 * a1.y + w1 * c1.y);
    o.u[6] = f2bf(w0 * a1.z + w1 * c1.z);
    o.u[7] = f2bf(w0 * a1.w + w1 * c1.w);

    const int b = R >> 14, h = (R >> 10) & 15, s = R & 1023;
    *(uint4*)&att[((size_t)((b * 1024 + s) * 16 + h)) * 128 + d0] = o.v;
}

// ---------------------------------------------------------------------------
extern "C" void kernel_launch(void* const* d_in, const int* in_sizes, int n_in,
                              void* d_out, int out_size, void* d_ws, size_t ws_size,
                              hipStream_t stream)
{
    const float* x  = (const float*)d_in[0];
    // d_in[1] = mask (bool tril): applied analytically — unused
    const float* Wq = (const float*)d_in[2];
    const float* bq = (const float*)d_in[3];
    const float* Wk = (const float*)d_in[4];
    const float* bk = (const float*)d_in[5];
    const float* Wv = (const float*)d_in[6];
    const float* bv = (const float*)d_in[7];
    const float* Wo = (const float*)d_in[8];
    const float* bo = (const float*)d_in[9];
    float* out = (float*)d_out;
    (void)d_ws; (void)ws_size;

    dim3 blk(256, 1, 1);
    hipLaunchKernelGGL(prep_kernel, dim3(4608), blk, 0, stream, x, Wq, Wk, Wv, Wo);
    hipLaunchKernelGGL(gemm128_kernel, dim3(24, 16), blk, 0, stream,
                       bq, bk, bv, (float*)nullptr, 0);
    hipLaunchKernelGGL(attn_kernel, dim3(32, 16, 2), blk, 0, stream);
    hipLaunchKernelGGL(merge_kernel, dim3(2048), blk, 0, stream);
    hipLaunchKernelGGL(gemm128_kernel, dim3(16, 16), blk, 0, stream,
                       bo, nullptr, nullptr, out, 1);
}

// Round 15
// 257.986 us; speedup vs baseline: 1.0506x; 1.0506x over previous
//
#include <hip/hip_runtime.h>

typedef __attribute__((ext_vector_type(8))) __bf16 bf16x8;
typedef __attribute__((ext_vector_type(8))) unsigned short u16x8;
typedef __attribute__((ext_vector_type(4))) float f32x4;

// Static device scratch (bf16):
//  xbf [2048][2048], WtQKV [3072][2048], WtO [2048][2048],
//  q [2048][2048], k [2048][512], vt [2][4][128][1024], att [2048][2048]
#define XBOFF 0
#define WQKVOFF (XBOFF + 2048 * 2048)
#define WOOFF   (WQKVOFF + 3072 * 2048)
#define QOFF    (WOOFF + 2048 * 2048)
#define KOFF    (QOFF + 2048 * 2048)
#define VTOFF   (KOFF + 2048 * 512)     // V pre-transposed: [b][g][d=128][s=1024]
#define AOFF    (VTOFF + 2048 * 512)
__device__ __align__(16) ushort g_scratch[AOFF + 2048 * 2048];

// nested (matryoshka) index -> full-layout index, H heads/groups, 128/head
__device__ __forceinline__ int nest_map(int n, int H) {
    int h = n >> 7, j = n & 127;
    if (j < 32) return h * 32 + j;
    if (j < 64) return H * 32 + h * 32 + (j - 32);
    return H * 64 + h * 64 + (j - 64);
}

__device__ __forceinline__ ushort f2bf(float f) {
    unsigned u = __builtin_bit_cast(unsigned, f);
    u += 0x7fffu + ((u >> 16) & 1u);
    return (ushort)(u >> 16);
}
__device__ __forceinline__ bf16x8 ld_frag(const ushort* p) {
    return __builtin_bit_cast(bf16x8, *(const u16x8*)p);
}
// bare v_exp_f32 (2^x) — __exp2f does not exist in HIP headers (R10 lesson)
__device__ __forceinline__ float exp2_fast(float x) {
    return __builtin_amdgcn_exp2f(x);
}
// async 16B global->LDS (m97 pattern); LDS base must be wave-uniform
__device__ __forceinline__ void glds16(const ushort* g, ushort* s) {
    __builtin_amdgcn_global_load_lds(
        (const __attribute__((address_space(1))) void*)g,
        (__attribute__((address_space(3))) void*)s, 16, 0, 0);
}

// ---------------------------------------------------------------------------
// Fused prep: one dispatch does x cvt + all 4 weight transposes.
// blocks [0,2048): x fp32->bf16.  [2048,3072): Wq^T  [3072,3328): Wk^T
// [3328,3584): Wv^T  [3584,4608): Wo^T (row-mapped)
// ---------------------------------------------------------------------------
__global__ __launch_bounds__(256) void prep_kernel(
    const float* __restrict__ x,
    const float* __restrict__ Wq, const float* __restrict__ Wk,
    const float* __restrict__ Wv, const float* __restrict__ Wo)
{
    const int bx = blockIdx.x;
    const int tid = threadIdx.x;

    if (bx < 2048) {   // ---- x convert ----
        size_t i = ((size_t)bx * 256 + tid) * 8;
        float4 f0 = *(const float4*)&x[i];
        float4 f1 = *(const float4*)&x[i + 4];
        union { uint4 v; ushort u[8]; } a;
        a.u[0] = f2bf(f0.x); a.u[1] = f2bf(f0.y); a.u[2] = f2bf(f0.z); a.u[3] = f2bf(f0.w);
        a.u[4] = f2bf(f1.x); a.u[5] = f2bf(f1.y); a.u[6] = f2bf(f1.z); a.u[7] = f2bf(f1.w);
        *(uint4*)&g_scratch[XBOFF + i] = a.v;
        return;
    }

    const float* W; int rowlen, H, mode, dstoff, t;
    if (bx < 3072)      { W = Wq; rowlen = 2048; H = 16; mode = 0; dstoff = WQKVOFF;               t = bx - 2048; }
    else if (bx < 3328) { W = Wk; rowlen = 512;  H = 4;  mode = 0; dstoff = WQKVOFF + 2048 * 2048; t = bx - 3072; }
    else if (bx < 3584) { W = Wv; rowlen = 512;  H = 4;  mode = 0; dstoff = WQKVOFF + 2560 * 2048; t = bx - 3328; }
    else                { W = Wo; rowlen = 2048; H = 16; mode = 1; dstoff = WOOFF;                 t = bx - 3584; }
    const int k0 = (t & 31) * 64;
    const int n0 = (t >> 5) * 64;

    __shared__ ushort T[64][66];
    const int r = tid >> 3, oct = tid & 7;

    #pragma unroll
    for (int rep = 0; rep < 2; ++rep) {
        int rr = r + rep * 32;
        int wrow = mode ? nest_map(k0 + rr, 16) : (k0 + rr);
        int wcol = mode ? (n0 + oct * 8) : nest_map(n0 + oct * 8, H);
        float4 f0 = *(const float4*)&W[(size_t)wrow * rowlen + wcol];
        float4 f1 = *(const float4*)&W[(size_t)wrow * rowlen + wcol + 4];
        ushort* d = &T[rr][oct * 8];
        d[0] = f2bf(f0.x); d[1] = f2bf(f0.y); d[2] = f2bf(f0.z); d[3] = f2bf(f0.w);
        d[4] = f2bf(f1.x); d[5] = f2bf(f1.y); d[6] = f2bf(f1.z); d[7] = f2bf(f1.w);
    }
    __syncthreads();
    #pragma unroll
    for (int rep = 0; rep < 2; ++rep) {
        int rr = r + rep * 32;
        union { uint4 v; ushort u[8]; } cv;
        #pragma unroll
        for (int i = 0; i < 8; ++i) cv.u[i] = T[oct * 8 + i][rr];
        *(uint4*)&g_scratch[dstoff + (size_t)(n0 + rr) * 2048 + k0 + oct * 8] = cv.v;
    }
}

// ---------------------------------------------------------------------------
// 128x128-tile GEMM, BK=64 (R13 — best measured). Counted-vmcnt 2-buffer
// pipeline: {s_waitcnt vmcnt(8); s_barrier; compute kt; s_barrier;
// STAGE(buf[kt&1], kt+2)} — next tile's 8 global_load_lds stay in flight
// across both barriers. LDS 2x32 KB. Rect per-XCD chunks (R7: FETCH
// 99->~56 MB). No setprio (R11/R12 A/B: hurts co-resident overlap).
// mode 0: A=xbf, Bt=WtQKV (N=3072) -> q | k natural | V^T global.
// mode 1: A=att, Bt=WtO -> fp32 out. V-blocks (n0>=2560) transpose their
// 128x128 output tile through LDS and write vt[b][g][d][s].
// ---------------------------------------------------------------------------
__global__ __launch_bounds__(256) void gemm128_kernel(
    const float* __restrict__ b0, const float* __restrict__ b1,
    const float* __restrict__ b2, float* __restrict__ oext, int mode)
{
    __shared__ __align__(16) ushort SH[2 * 16384];

    const int gx = gridDim.x;             // n tiles (mult of 4)
    const int gy = gridDim.y;             // m tiles (mult of 2)
    const int id = blockIdx.x + gx * blockIdx.y;
    const int xcd = id & 7, idl = id >> 3;
    const int CM = gy >> 1, CN = gx >> 2; // 2x4 chunk grid over 8 XCDs
    const int m_idx = (xcd >> 2) * CM + (idl % CM);
    const int n_idx = (xcd & 3) * CN + (idl / CM);
    const int n0 = n_idx * 128;
    const int m0 = m_idx * 128;

    const int tid = threadIdx.x;
    const int lane = tid & 63, wid = tid >> 6;
    const int wm = wid & 1, wn = wid >> 1;
    const int quad = lane >> 4, l16 = lane & 15;

    const ushort* A  = g_scratch + (mode ? AOFF : XBOFF);
    const ushort* Bt = g_scratch + (mode ? WOOFF : WQKVOFF);

    const bool vpath = (mode == 0) && (n0 >= 2560);
    const float* bias; ushort* outS = nullptr; int c0, oldim, H;
    if (mode == 1)      { bias = b0; c0 = n0; oldim = 2048; H = 0; }
    else if (n0 < 2048) { bias = b0; outS = g_scratch + QOFF; c0 = n0;        oldim = 2048; H = 16; }
    else if (n0 < 2560) { bias = b1; outS = g_scratch + KOFF; c0 = n0 - 2048; oldim = 512;  H = 4; }
    else                { bias = b2; outS = nullptr;          c0 = n0 - 2560; oldim = 512;  H = 4; }

    const int lrow = lane >> 3;
    const int lchunk = (lane & 7) ^ (lrow & 7);

    f32x4 acc[4][4];
    #pragma unroll
    for (int a = 0; a < 4; ++a)
        #pragma unroll
        for (int c = 0; c < 4; ++c) acc[a][c] = f32x4{0.f, 0.f, 0.f, 0.f};

    auto STAGE = [&](int buf, int kt) {
        const int k0 = kt * 64;
        ushort* as_ = SH + buf * 16384;
        ushort* bs_ = as_ + 8192;
        #pragma unroll
        for (int it = 0; it < 4; ++it) {      // A: 128 rows
            int rb = it * 32 + wid * 8;       // wave-uniform row base
            int r  = rb + lrow;
            glds16(&A[(size_t)(m0 + r) * 2048 + k0 + lchunk * 8], &as_[rb * 64]);
        }
        #pragma unroll
        for (int it = 0; it < 4; ++it) {      // B: 128 rows
            int rb = it * 32 + wid * 8;
            int r  = rb + lrow;
            glds16(&Bt[(size_t)(n0 + r) * 2048 + k0 + lchunk * 8], &bs_[rb * 64]);
        }
    };

    STAGE(0, 0);
    STAGE(1, 1);

    for (int kt = 0; kt < 32; ++kt) {
        if (kt < 31) asm volatile("s_waitcnt vmcnt(8)" ::: "memory");
        else         asm volatile("s_waitcnt vmcnt(0)" ::: "memory");
        __builtin_amdgcn_s_barrier();         // all waves' kt-loads landed

        const ushort* as_ = SH + (kt & 1) * 16384;
        const ushort* bs_ = as_ + 8192;
        #pragma unroll
        for (int kc = 0; kc < 2; ++kc) {
            bf16x8 af[4], bf[4];
            #pragma unroll
            for (int s = 0; s < 4; ++s) {
                int ra = wm * 64 + s * 16 + l16;
                int rbv = wn * 64 + s * 16 + l16;
                int ch = kc * 4 + quad;
                af[s] = ld_frag(&as_[ra * 64 + ((ch ^ (ra & 7)) * 8)]);
                bf[s] = ld_frag(&bs_[rbv * 64 + ((ch ^ (rbv & 7)) * 8)]);
            }
            #pragma unroll
            for (int sm = 0; sm < 4; ++sm)
                #pragma unroll
                for (int sn = 0; sn < 4; ++sn)
                    acc[sm][sn] = __builtin_amdgcn_mfma_f32_16x16x32_bf16(
                        af[sm], bf[sn], acc[sm][sn], 0, 0, 0);
        }
        __builtin_amdgcn_s_barrier();         // all reads of buf[kt&1] done
        if (kt <= 29) STAGE(kt & 1, kt + 2);  // safe to overwrite; async
    }
    __syncthreads();   // drain before epilogue reuses SH

    if (vpath) {
        // transpose 128x128 tile through SH (xor-swizzled), write vt[b][g][d][s]
        #pragma unroll
        for (int sm = 0; sm < 4; ++sm)
        #pragma unroll
        for (int sn = 0; sn < 4; ++sn)
        #pragma unroll
        for (int i = 0; i < 4; ++i) {
            int r = wm * 64 + sm * 16 + quad * 4 + i;       // spos-local
            int loc = wn * 64 + sn * 16 + l16;              // d-local (=g*128+d col)
            float v = acc[sm][sn][i] + bias[nest_map(c0 + loc, 4)];
            SH[loc * 128 + (r ^ ((loc & 7) << 3))] = f2bf(v);
        }
        __syncthreads();
        const int dloc = tid >> 1, half = tid & 1;
        const int gg = c0 >> 7, bb = m0 >> 10, sb = m0 & 1023;
        ushort* vt = g_scratch + VTOFF;
        #pragma unroll
        for (int j = 0; j < 8; ++j) {
            int r = half * 64 + j * 8;
            uint4 v = *(uint4*)&SH[dloc * 128 + (r ^ ((dloc & 7) << 3))];
            *(uint4*)&vt[((size_t)((bb * 4 + gg) * 128 + dloc)) * 1024 + sb + r] = v;
        }
    } else {
        #pragma unroll
        for (int sm = 0; sm < 4; ++sm)
        #pragma unroll
        for (int sn = 0; sn < 4; ++sn)
        #pragma unroll
        for (int i = 0; i < 4; ++i) {
            int row = m0 + wm * 64 + sm * 16 + quad * 4 + i;
            int loc = wn * 64 + sn * 16 + l16;
            float v = acc[sm][sn][i];
            if (mode == 1) {
                oext[(size_t)row * 2048 + c0 + loc] = v + bias[c0 + loc];
            } else {
                v += bias[nest_map(c0 + loc, H)];
                outS[(size_t)row * oldim + c0 + loc] = f2bf(v);
            }
        }
    }
}

// ---------------------------------------------------------------------------
// Matryoshka flash attention (R13 — best measured). Base-2 softmax (log2e
// folded into scales, bare v_exp via __builtin_amdgcn_exp2f). Grid
// (16,16,2), 4 waves; qt anti-correlated; LDS flat + XOR-swizzled
// (40960 B); s_setprio around MFMA; MFMA row-sum of P.
// Split-K / half-block / async-dbuf variants all measured SLOWER
// (R2/R4/R8/R14): this 4-wave 64-row structure is at its scheduler floor.
// ---------------------------------------------------------------------------
__global__ __launch_bounds__(256) void attn_kernel()
{
    const ushort* qb = g_scratch + QOFF;   // [B,S,16,128] nested
    const ushort* kb = g_scratch + KOFF;   // [B,S,4,128]
    const ushort* vt = g_scratch + VTOFF;  // [B,4,128,1024]
    ushort* att = g_scratch + AOFF;        // [B,S,16,128] nested

    __shared__ __align__(16) ushort Ks[64 * 128];
    __shared__ __align__(16) ushort Vt[128 * 64];
    __shared__ __align__(16) ushort Ps[64 * 64];

    const int x = blockIdx.x, h = blockIdx.y, b = blockIdx.z;
    const int ks_half = x >> 1;
    const int qt = ((x ^ b) & 1) ? ks_half : 15 - ks_half;
    const int g = h >> 2;
    const int q0 = qt * 64;
    const int tid = threadIdx.x;
    const int lane = tid & 63, w = tid >> 6;
    const int quad = lane >> 4, l16 = lane & 15;

    // base-2-domain scales: (1/sqrt(d)) * log2(e)
    const float sc0 = 0.25503639f;
    const float sc1 = 0.18033688f;
    const float sc2 = 0.12751820f;

    bf16x8 qa[4];
    {
        const ushort* qrow =
            qb + ((size_t)((b * 1024 + q0 + w * 16 + l16) * 16 + h)) * 128;
        #pragma unroll
        for (int kc = 0; kc < 4; ++kc)
            qa[kc] = ld_frag(qrow + kc * 32 + quad * 8);
    }

    float m_s[3][4], l_s[3][4];
    #pragma unroll
    for (int l = 0; l < 3; ++l)
        #pragma unroll
        for (int i = 0; i < 4; ++i) { m_s[l][i] = -1e9f; l_s[l][i] = 0.0f; }
    f32x4 oacc[8];
    #pragma unroll
    for (int t2 = 0; t2 < 8; ++t2) oacc[t2] = f32x4{0.f, 0.f, 0.f, 0.f};
    const f32x4 fz = {0.f, 0.f, 0.f, 0.f};
    const bf16x8 ones = __builtin_bit_cast(bf16x8, u16x8{
        0x3F80, 0x3F80, 0x3F80, 0x3F80, 0x3F80, 0x3F80, 0x3F80, 0x3F80});

    for (int kt = 0; kt <= qt; ++kt) {
        const int k0 = kt * 64;
        {   // stage K (b128, swizzled) + Vt from global vt (b128, swizzled)
            int r16 = tid >> 4, oct16 = tid & 15;
            #pragma unroll
            for (int rep = 0; rep < 4; ++rep) {
                int row = r16 + rep * 16;
                *(uint4*)&Ks[row * 128 + ((oct16 ^ (row & 7)) * 8)] =
                    *(const uint4*)&kb[(size_t)((b * 1024 + k0 + row) * 4 + g) * 128 + oct16 * 8];
            }
            int oct = tid & 7, dr = tid >> 3;
            #pragma unroll
            for (int rep = 0; rep < 4; ++rep) {
                int d = dr + rep * 32;
                *(uint4*)&Vt[d * 64 + ((oct ^ (d & 7)) * 8)] =
                    *(const uint4*)&vt[((size_t)((b * 4 + g) * 128 + d)) * 1024 + k0 + oct * 8];
            }
        }
        __syncthreads();

        const bool diag = (kt == qt);

        // QK^T, cumulative snapshots: s0 (dims 0:32), s1 (0:64), s2 (0:128)
        f32x4 s0[4], s1[4], s2[4];
        __builtin_amdgcn_s_setprio(1);
        #pragma unroll
        for (int n = 0; n < 4; ++n) {
            int r = n * 16 + l16;
            s0[n] = __builtin_amdgcn_mfma_f32_16x16x32_bf16(
                qa[0], ld_frag(&Ks[r * 128 + (((0 + quad) ^ (r & 7)) * 8)]), fz, 0, 0, 0);
        }
        #pragma unroll
        for (int n = 0; n < 4; ++n) {
            int r = n * 16 + l16;
            s1[n] = __builtin_amdgcn_mfma_f32_16x16x32_bf16(
                qa[1], ld_frag(&Ks[r * 128 + (((4 + quad) ^ (r & 7)) * 8)]), s0[n], 0, 0, 0);
        }
        #pragma unroll
        for (int n = 0; n < 4; ++n) {
            int r = n * 16 + l16;
            s2[n] = __builtin_amdgcn_mfma_f32_16x16x32_bf16(
                qa[2], ld_frag(&Ks[r * 128 + (((8 + quad) ^ (r & 7)) * 8)]), s1[n], 0, 0, 0);
        }
        #pragma unroll
        for (int n = 0; n < 4; ++n) {
            int r = n * 16 + l16;
            s2[n] = __builtin_amdgcn_mfma_f32_16x16x32_bf16(
                qa[3], ld_frag(&Ks[r * 128 + (((12 + quad) ^ (r & 7)) * 8)]), s2[n], 0, 0, 0);
        }
        __builtin_amdgcn_s_setprio(0);

        // interleaved 3-level online softmax, base-2 domain (ILP chains)
        float sv[3][4][4], mx[3][4];
        #pragma unroll
        for (int l = 0; l < 3; ++l)
            #pragma unroll
            for (int i = 0; i < 4; ++i) mx[l][i] = -1e9f;
        #pragma unroll
        for (int n = 0; n < 4; ++n)
            #pragma unroll
            for (int i = 0; i < 4; ++i) {
                bool msk = diag &&
                    (k0 + n * 16 + l16 > q0 + w * 16 + quad * 4 + i);
                float x0 = msk ? -1e9f : s0[n][i] * sc0;
                float x1 = msk ? -1e9f : s1[n][i] * sc1;
                float x2 = msk ? -1e9f : s2[n][i] * sc2;
                sv[0][n][i] = x0; mx[0][i] = fmaxf(mx[0][i], x0);
                sv[1][n][i] = x1; mx[1][i] = fmaxf(mx[1][i], x1);
                sv[2][n][i] = x2; mx[2][i] = fmaxf(mx[2][i], x2);
            }
        #pragma unroll
        for (int d = 1; d < 16; d <<= 1)
            #pragma unroll
            for (int l = 0; l < 3; ++l)
                #pragma unroll
                for (int i = 0; i < 4; ++i)
                    mx[l][i] = fmaxf(mx[l][i], __shfl_xor(mx[l][i], d, 64));
        float al[3][4];
        #pragma unroll
        for (int l = 0; l < 3; ++l)
            #pragma unroll
            for (int i = 0; i < 4; ++i) {
                float mn = fmaxf(m_s[l][i], mx[l][i]);
                al[l][i] = exp2_fast(m_s[l][i] - mn);
                m_s[l][i] = mn;
            }
        #pragma unroll
        for (int n = 0; n < 4; ++n)
            #pragma unroll
            for (int l = 0; l < 3; ++l)
                #pragma unroll
                for (int i = 0; i < 4; ++i)
                    sv[l][n][i] = exp2_fast(sv[l][n][i] - m_s[l][i]);
        #pragma unroll
        for (int t = 0; t < 8; ++t) {
            int lvl = (t < 2) ? 0 : (t < 4) ? 1 : 2;
            #pragma unroll
            for (int i = 0; i < 4; ++i) oacc[t][i] *= al[lvl][i];
        }

        // per-level Ps roundtrip + PV + MFMA row-sum (same-wave in-order LDS)
        f32x4 racc[3];
        const int obase[3] = {0, 2, 4}, onts[3] = {2, 2, 4}, voffs[3] = {0, 32, 64};
        #pragma unroll
        for (int l = 0; l < 3; ++l) {
            #pragma unroll
            for (int n = 0; n < 4; ++n)
                #pragma unroll
                for (int i = 0; i < 4; ++i) {
                    int prow = w * 16 + quad * 4 + i;
                    int col = n * 16 + l16;
                    Ps[prow * 64 + ((((col >> 3) ^ (prow & 7)) << 3) | (col & 7))] =
                        f2bf(sv[l][n][i]);
                }
            racc[l] = fz;
            __builtin_amdgcn_s_setprio(1);
            #pragma unroll
            for (int kc = 0; kc < 2; ++kc) {
                int prow = w * 16 + l16;
                bf16x8 pa = ld_frag(&Ps[prow * 64 + (((kc * 4 + quad) ^ (prow & 7)) * 8)]);
                racc[l] = __builtin_amdgcn_mfma_f32_16x16x32_bf16(
                    pa, ones, racc[l], 0, 0, 0);
                #pragma unroll
                for (int t = 0; t < 4; ++t) {
                    if (t < onts[l]) {
                        int vd = voffs[l] + t * 16 + l16;
                        bf16x8 vf = ld_frag(&Vt[vd * 64 + (((kc * 4 + quad) ^ (vd & 7)) * 8)]);
                        oacc[obase[l] + t] = __builtin_amdgcn_mfma_f32_16x16x32_bf16(
                            pa, vf, oacc[obase[l] + t], 0, 0, 0);
                    }
                }
            }
            __builtin_amdgcn_s_setprio(0);
        }
        #pragma unroll
        for (int l = 0; l < 3; ++l)
            #pragma unroll
            for (int i = 0; i < 4; ++i)
                l_s[l][i] = l_s[l][i] * al[l][i] + racc[l][i];
        __syncthreads();   // WAR: Ks/Vt reads done before next staging
    }

    float inv[3][4];
    #pragma unroll
    for (int l = 0; l < 3; ++l)
        #pragma unroll
        for (int i = 0; i < 4; ++i) {
            float L = l_s[l][i];
            inv[l][i] = (L > 0.f) ? (1.0f / L) : 0.f;
        }
    #pragma unroll
    for (int t = 0; t < 8; ++t) {
        int lvl = (t < 2) ? 0 : (t < 4) ? 1 : 2;
        #pragma unroll
        for (int i = 0; i < 4; ++i) {
            int srow = q0 + w * 16 + quad * 4 + i;
            att[(size_t)((b * 1024 + srow) * 16 + h) * 128 + t * 16 + l16] =
                f2bf(oacc[t][i] * inv[lvl][i]);
        }
    }
}

// ---------------------------------------------------------------------------
extern "C" void kernel_launch(void* const* d_in, const int* in_sizes, int n_in,
                              void* d_out, int out_size, void* d_ws, size_t ws_size,
                              hipStream_t stream)
{
    const float* x  = (const float*)d_in[0];
    // d_in[1] = mask (bool tril): applied analytically — unused
    const float* Wq = (const float*)d_in[2];
    const float* bq = (const float*)d_in[3];
    const float* Wk = (const float*)d_in[4];
    const float* bk = (const float*)d_in[5];
    const float* Wv = (const float*)d_in[6];
    const float* bv = (const float*)d_in[7];
    const float* Wo = (const float*)d_in[8];
    const float* bo = (const float*)d_in[9];
    float* out = (float*)d_out;
    (void)d_ws; (void)ws_size;

    dim3 blk(256, 1, 1);
    hipLaunchKernelGGL(prep_kernel, dim3(4608), blk, 0, stream, x, Wq, Wk, Wv, Wo);
    hipLaunchKernelGGL(gemm128_kernel, dim3(24, 16), blk, 0, stream,
                       bq, bk, bv, (float*)nullptr, 0);
    hipLaunchKernelGGL(attn_kernel, dim3(16, 16, 2), blk, 0, stream);
    hipLaunchKernelGGL(gemm128_kernel, dim3(16, 16), blk, 0, stream,
                       bo, nullptr, nullptr, out, 1);
}